// Round 15
// baseline (519.520 us; speedup 1.0000x reference)
//
#include <hip/hip_runtime.h>
#include <stdint.h>

#define GAS __attribute__((address_space(1)))
#define LAS __attribute__((address_space(3)))

typedef __attribute__((ext_vector_type(8))) short short8;
typedef __attribute__((ext_vector_type(4))) float float4v;
typedef __attribute__((ext_vector_type(4))) unsigned int uint4v;

__device__ __forceinline__ unsigned short f2bf(float f) {
  union { float f; unsigned int u; } v; v.f = f;
  unsigned int r = v.u + 0x7fffu + ((v.u >> 16) & 1u);
  return (unsigned short)(r >> 16);
}

__device__ __forceinline__ void async_g2l16(const void* g, void* l) {
  __builtin_amdgcn_global_load_lds((const GAS unsigned int*)g,
                                   (LAS unsigned int*)l, 16, 0, 0);
}

__device__ __forceinline__ void vmem_drain() {
  asm volatile("s_waitcnt vmcnt(0)" ::: "memory");
}

// ---- Kernel P: fused prep. Blocks 0..255: knorm_y; 256..2303: ktrans_x. ----
// R14 knorm_y rewrite: block = (o-quad og2, dy-segment seg). Old version did
// 1M scalar 2B stores at 8KB stride; each y_t2 64B line was shared by 4
// DIFFERENT o-blocks (cross-XCD write-allocate RMW). Now: thread writes full
// short8 (16B); lanes u,u+8,u+16,u+24 of one wave instr fill one 64B line
// (quad owns the 4-aligned ol run). Reads: 8 x 4B gathers, L2-hot, each
// (o,c,dy) line fully consumed within the block (t range = one dy).
// y_t2 element map (16x16x32 B-operand): dst = t*4096 + (og*2+cb)*512 +
// (q*16+ol)*8 + j, with o = og*16+ol, c = cb*32+q*8+j, t = dy*16+dx.
// ktrans_x: float4-vectorized (R12), 3-bit XOR chunk swizzle (0 conflicts).
__global__ void kprep(const float* __restrict__ x, const float* __restrict__ y,
                      unsigned short* __restrict__ x_t, unsigned short* __restrict__ y_t2,
                      float* __restrict__ s) {
  int b = blockIdx.x;
  int tid = threadIdx.x;
  if (b < 256) {
    // ---------------- knorm_y: block = (og2 = o/4, seg = dy) ----------------
    int og2 = b >> 4, seg = b & 15;
    int wv = tid >> 6, ln = tid & 63;
    __shared__ float rnl[4];
    // Phase 1: wave wv reduces the norm of o = og2*4 + wv (L2-hot).
    {
      int o = og2 * 4 + wv;
      const float4v* yo4 = (const float4v*)(y + o * 16384);
      float sm = 0.f;
      for (int p = ln; p < 4096; p += 64) {
        float4v t4 = yo4[p];
        sm += t4[0] * t4[0] + t4[1] * t4[1] + t4[2] * t4[2] + t4[3] * t4[3];
      }
      for (int off = 32; off; off >>= 1) sm += __shfl_down(sm, off, 64);
      if (ln == 0) rnl[wv] = 1.0f / sqrtf(sm);
    }
    __syncthreads();
    // Phase 2: 512 short8 chunks (16 t x 8 cbq x 4 oo), 2 per thread.
#pragma unroll
    for (int k = 0; k < 2; ++k) {
      int u = k * 256 + tid;
      int t = seg * 16 + (u >> 5);   // dy = seg, dx = u>>5
      int rest = u & 31;
      int oo = rest >> 3, cbq = rest & 7;
      int cb = cbq >> 2, q = cbq & 3;
      int o = og2 * 4 + oo;
      int og = o >> 4, ol = o & 15;
      float rn = rnl[oo];
      const float* ysrc = y + (size_t)o * 16384 + (size_t)(cb * 32 + q * 8) * 256 + t;
      short8 o8;
#pragma unroll
      for (int j = 0; j < 8; ++j) o8[j] = (short)f2bf(ysrc[j * 256] * rn);
      ((short8*)y_t2)[(size_t)t * 512 + (og * 2 + cb) * 64 + q * 16 + ol] = o8;
    }
    return;
  }
  // ---------------- ktrans_x: thread (wq, cg) = 4 w x 8 c ----------------
  int bb = b - 256;
  int h = bb & 127, n = bb >> 7;
  __shared__ __align__(16) unsigned short tb[8192];
  __shared__ float sb[1024];  // [cg][w] partial sums
  const float* xb = x + ((size_t)n * 64) * 16384 + h * 128;
  int wq = tid & 31, cg = tid >> 5;
  float4v v[8];
#pragma unroll
  for (int j = 0; j < 8; ++j)
    v[j] = *(const float4v*)(xb + (size_t)(cg * 8 + j) * 16384 + wq * 4);
  float4v a = (float4v){0.f, 0.f, 0.f, 0.f};
#pragma unroll
  for (int j = 0; j < 8; ++j) {
    a[0] += v[j][0] * v[j][0];
    a[1] += v[j][1] * v[j][1];
    a[2] += v[j][2] * v[j][2];
    a[3] += v[j][3] * v[j][3];
  }
#pragma unroll
  for (int k = 0; k < 4; ++k) sb[cg * 128 + wq * 4 + k] = a[k];
#pragma unroll
  for (int k = 0; k < 4; ++k) {
    int w = wq * 4 + k;
    short8 tmp;
#pragma unroll
    for (int j = 0; j < 8; ++j) tmp[j] = (short)f2bf(v[j][k]);
    int chunk = cg ^ (w & 7);
    *(short8*)(tb + w * 64 + chunk * 8) = tmp;
  }
  __syncthreads();
  uint4v* dst = (uint4v*)(x_t + ((size_t)(n * 128 + h)) * 8192);
  const uint4v* src = (const uint4v*)tb;
  for (int idx = tid; idx < 1024; idx += 256) dst[idx] = src[idx];
  if (tid < 128) {
    float ssum = 0.f;
#pragma unroll
    for (int g = 0; g < 8; ++g) ssum += sb[g * 128 + tid];
    s[((size_t)(n * 128 + h)) * 128 + tid] = ssum;
  }
}

// ---------------- Kernel E: main implicit-GEMM conv + fused invn ----------
// (R12 structure, unchanged: verified ~400us floor, cross-session noise ±10.
// XCD swizzle, depth-1 B ping-pong, vmcnt(4), sched_barrier-pinned stageA,
// knorm_x folded into the prologue, direct-store epilogue, verified C/D map.)
__launch_bounds__(256, 4)
__global__ void kconv(const unsigned short* __restrict__ x_t,
                      const unsigned short* __restrict__ y_t2,
                      const float* __restrict__ s,
                      float* __restrict__ out) {
  // XCD-chunked swizzle: hw round-robins linear wg id across 8 XCDs.
  int lin = blockIdx.y * 113 + blockIdx.x;
  int wg = (lin & 7) * 226 + (lin >> 3);   // bijective: 1808 = 8*226
  int i = wg % 113;
  int n = wg / 113;
  int tid = threadIdx.x;
  int lane = tid & 63, wave = tid >> 6;
  int lane15 = lane & 15, q = lane >> 4;
  int wrow = wave >> 1, wcol = wave & 1;

  __shared__ __align__(16) char smem[32768];
  __shared__ float csum[128];
  __shared__ __align__(16) float ivs[128];
  char* const A0 = smem;
  char* const A1 = smem + 16384;

  const char* xrow0 = (const char*)(x_t + ((size_t)(n * 128 + i)) * 8192);

  auto stageA = [&](int dy, char* buf) {
    const char* src = xrow0 + (size_t)dy * 16384;
#pragma unroll
    for (int it = 0; it < 4; ++it) {
      int chunk = it * 256 + wave * 64;  // wave-uniform LDS base
      async_g2l16(src + (chunk + lane) * 16, buf + chunk * 16);
    }
  };

  const short8* ybase = (const short8*)(y_t2 + (size_t)wcol * 2048 + (size_t)lane * 8);
  auto loadB = [&](int t, short8 bf[2][2]) {
    const short8* p = ybase + (size_t)t * 512;  // 512 short8 = 4096 shorts per t
    bf[0][0] = p[0];
    bf[0][1] = p[64];
    bf[1][0] = p[128];
    bf[1][1] = p[192];
  };

  float4v acc[4][2];
#pragma unroll
  for (int mt = 0; mt < 4; ++mt)
#pragma unroll
    for (int nt = 0; nt < 2; ++nt) acc[mt][nt] = (float4v){0.f, 0.f, 0.f, 0.f};

  int abase[4];
#pragma unroll
  for (int mt = 0; mt < 4; ++mt) abase[mt] = (wrow * 64 + mt * 16 + lane15) * 128;

  short8 b0[2][2], b1[2][2];
  stageA(0, A0);
  loadB(0, b0);

  // ---- fused knorm_x (separable 16x16 box sum of s -> 1/sqrt), hidden
  // under the initial stage/load latency ----
  {
    const float* sp = s + ((size_t)(n * 128 + i)) * 128;
    if (tid < 128) {
      float a = 0.f;
#pragma unroll
      for (int dy = 0; dy < 16; ++dy) a += sp[dy * 128 + tid];
      csum[tid] = a;
    }
    __syncthreads();
    if (tid < 113) {
      float a = 0.f;
#pragma unroll
      for (int dx = 0; dx < 16; ++dx) a += csum[tid + dx];
      ivs[tid] = 1.0f / sqrtf(a);
    }
  }

  vmem_drain();
  __syncthreads();

#pragma unroll 1
  for (int dy = 0; dy < 16; ++dy) {
    char* Ab = (dy & 1) ? A1 : A0;
    if (dy < 15) {
      __builtin_amdgcn_sched_barrier(0);
      stageA(dy + 1, (dy & 1) ? A0 : A1);
      __builtin_amdgcn_sched_barrier(0);
    }
#pragma unroll
    for (int dx = 0; dx < 16; ++dx) {
      int t = dy * 16 + dx;
      // compile-time ping-pong after unroll: no register copies
      short8(&bc)[2][2] = (dx & 1) ? b1 : b0;
      short8(&bn)[2][2] = (dx & 1) ? b0 : b1;
      if (t < 255) loadB(t + 1, bn);
      int xr = (lane15 + dx) & 7;
#pragma unroll
      for (int cb = 0; cb < 2; ++cb) {
        int aoff = dx * 128 + (((q + cb * 4) ^ xr) << 4);
#pragma unroll
        for (int mt = 0; mt < 4; ++mt) {
          short8 a = *(const short8*)(Ab + abase[mt] + aoff);
          acc[mt][0] = __builtin_amdgcn_mfma_f32_16x16x32_bf16(a, bc[0][cb], acc[mt][0], 0, 0, 0);
          acc[mt][1] = __builtin_amdgcn_mfma_f32_16x16x32_bf16(a, bc[1][cb], acc[mt][1], 0, 0, 0);
        }
      }
    }
    // Relaxed drain: all stageA LDS-DMA (pinned oldest by sched_barrier) must
    // land; the 4 newest (dx=15 loadB for next dy) may stay in flight.
    asm volatile("s_waitcnt vmcnt(4)" ::: "memory");
    __syncthreads();
  }

  // Epilogue: direct stores, invn (from LDS) + relu fused.
  // o = wcol*32 + nt*16 + lane15; j = wrow*64 + mt*16 + q*4 + reg.
  float* op = out + (size_t)n * 64 * 12769 + (size_t)i * 113;
  int obase = wcol * 32 + lane15;
  int jb = wrow * 64 + q * 4;
#pragma unroll
  for (int mt = 0; mt < 4; ++mt) {
    int j0 = jb + mt * 16;
    if (j0 <= 108) {
      float4v iv = *(const float4v*)(ivs + j0);
#pragma unroll
      for (int nt = 0; nt < 2; ++nt) {
        int o = obase + nt * 16;
        float4v v = acc[mt][nt];
        float4v r;
        r[0] = fmaxf(v[0] * iv[0], 0.f);
        r[1] = fmaxf(v[1] * iv[1], 0.f);
        r[2] = fmaxf(v[2] * iv[2], 0.f);
        r[3] = fmaxf(v[3] * iv[3], 0.f);
        *(float4v*)(op + (size_t)o * 12769 + j0) = r;
      }
    } else if (j0 == 112) {
      float ivv = ivs[112];
#pragma unroll
      for (int nt = 0; nt < 2; ++nt) {
        int o = obase + nt * 16;
        op[(size_t)o * 12769 + 112] = fmaxf(acc[mt][nt][0] * ivv, 0.f);
      }
    }
  }
}

extern "C" void kernel_launch(void* const* d_in, const int* in_sizes, int n_in,
                              void* d_out, int out_size, void* d_ws, size_t ws_size,
                              hipStream_t stream) {
  const float* x = (const float*)d_in[0];
  const float* y = (const float*)d_in[1];
  float* out = (float*)d_out;
  char* ws = (char*)d_ws;
  unsigned short* x_t = (unsigned short*)ws;                 // 33,554,432 B
  unsigned short* y_t2 = (unsigned short*)(ws + 33554432);   //  2,097,152 B
  float* s = (float*)(ws + 35651584);                        //  1,048,576 B

  hipLaunchKernelGGL(kprep, dim3(2304), dim3(256), 0, stream, x, y, x_t, y_t2, s);
  hipLaunchKernelGGL(kconv, dim3(113, 16), dim3(256), 0, stream, x_t, y_t2, s, out);
}